// Round 4
// baseline (37.829 us; speedup 1.0000x reference)
//
#include <hip/hip_runtime.h>

#define CIN  64
#define COUT 64
#define Hn   128
#define Wn   128
#define HW   (Hn * Wn)
#define KDIM 576
#define WROW 1152   // fallback Wtb row stride in bytes
#define EROW 640    // fallback emap row stride in bytes

#define NRQ 5        // staged rows
#define NCQ 36       // staged cols
#define NCHUNKQ (NRQ * NCQ * 8)   // 16B input chunks = 1440
#define TILE_BYTES (NCHUNKQ * 32) // split tile: 46080 bytes (256B/pixel)

typedef __attribute__((ext_vector_type(8))) short bf16x8;
typedef __attribute__((ext_vector_type(4))) float f32x4;
typedef __attribute__((ext_vector_type(2))) float f32x2;

__device__ __forceinline__ unsigned short f2bf(float f) {
    unsigned u = __float_as_uint(f);
    unsigned r = u + 0x7FFFu + ((u >> 16) & 1u);   // RNE
    return (unsigned short)(r >> 16);
}
__device__ __forceinline__ unsigned pk2(float a, float b) {
    return (unsigned)f2bf(a) | ((unsigned)f2bf(b) << 16);
}
// half-up bf16 pair pack via v_perm (validated r2/r3, bit-identical to
// ((ua+0x8000)>>16)|((ub+0x8000)&0xFFFF0000)).
__device__ __forceinline__ unsigned pk2h(float a, float b) {
    unsigned ua = __float_as_uint(a) + 0x8000u;
    unsigned ub = __float_as_uint(b) + 0x8000u;
    return __builtin_amdgcn_perm(ub, ua, 0x07060302u);
}

// ============================ FAST PATH =====================================

// Fused prep (r1/r3-validated): blocks [0,1024) transpose x; [1024,1168) Wtb2.
__global__ __launch_bounds__(256) void prep_fused(
    const float* __restrict__ x, const float* __restrict__ weight,
    unsigned short* __restrict__ xt, unsigned short* __restrict__ Wtb2)
{
    __shared__ float fbuf[64][65];
    if (blockIdx.x >= 1024) {
        int e = (blockIdx.x - 1024) * 256 + threadIdx.x;
        if (e < COUT * KDIM) {
            int o = e / KDIM, k = e % KDIM;
            int n = k >> 6, c = k & 63;
            int u = n % 3, v = n / 3;
            float w0 = weight[((o * CIN + c) * 3 + 0) * 3 + v];
            float w2 = weight[((o * CIN + c) * 3 + 2) * 3 + v];
            float val = (u == 0) ? w0 : ((u == 1) ? (-w0 - w2) : w2);
            int s = c >> 5;
            int ce = c & 31;
            Wtb2[((n * 2 + s) * 64 + o) * 32 + ce] = f2bf(val);
        }
        return;
    }
    const int blk = blockIdx.x;            // b*256 + h*2 + wtile
    const int b   = blk >> 8;
    const int rem = blk & 255;
    const int h   = rem >> 1;
    const int w0  = (rem & 1) << 6;
    const int t   = threadIdx.x;
    {
        int wq = t & 63, cq = t >> 6;
        const float* xp = x + ((size_t)(b * CIN + cq * 16) * Hn + h) * Wn + w0 + wq;
        #pragma unroll
        for (int r = 0; r < 16; ++r)
            fbuf[wq][cq * 16 + r] = xp[(size_t)r * HW];
    }
    __syncthreads();
    {
        int wq = t >> 2, q = t & 3;
        const float* row = &fbuf[wq][q * 16];
        uint4 d0, d1;
        d0.x = pk2(row[0],  row[1]);  d0.y = pk2(row[2],  row[3]);
        d0.z = pk2(row[4],  row[5]);  d0.w = pk2(row[6],  row[7]);
        d1.x = pk2(row[8],  row[9]);  d1.y = pk2(row[10], row[11]);
        d1.z = pk2(row[12], row[13]); d1.w = pk2(row[14], row[15]);
        unsigned short* op = xt + ((size_t)(b * Hn + h) * Wn + w0 + wq) * 64 + q * 16;
        *reinterpret_cast<uint4*>(op)     = d0;
        *reinterpret_cast<uint4*>(op + 8) = d1;
    }
}

// axis geometry (validated r5/r6): local tile indices + bilinear weights.
template<int D>
__device__ __forceinline__ void axis_pts(float s, int base1, int org,
                                         int& l0, int& l1, float& w0, float& w1)
{
    if (D) {
        float p  = (float)D * s + (float)base1;
        float f  = floorf(p);
        float q0 = fminf(fmaxf(f,       0.f), 129.f);
        float q1 = fminf(fmaxf(f + 1.f, 0.f), 129.f);
        w0 = 1.f + (q0 - p);  w1 = 1.f - (q1 - p);
        int i0 = (int)q0, i1 = (int)q1;
        if (i0 < 1 || i0 > 128) w0 = 0.f;
        if (i1 < 1 || i1 > 128) w1 = 0.f;
        l0 = min(max(i0 - 1, 0), 127) - org;
        l1 = min(max(i1 - 1, 0), 127) - org;
    } else {
        l0 = base1 - 1 - org;  w0 = 1.f;
        l1 = l0;               w1 = 0.f;
    }
}

// point -> two swizzled byte offsets into the SPLIT tile.
// Split layout (this round): pixel rc occupies 256B; lo-plane [0,128) holds
// 8 slots x 16B of even-channel dwords (bf16 pre-shifted <<16), hi-plane
// [128,256) the odd-channel dwords (bf16 pre-masked to high half).  Slot s
// sits at ((s ^ (col&7))<<4) within its plane — same XOR algebra as before,
// so offL/offH expressions are unchanged except the <<8 pixel stride; the
// +128 hi-plane companion folds into the ds_read offset immediate.
__device__ __forceinline__ void mkpt(int lr, int lc, int g16,
                                     unsigned& offL, unsigned& offH) {
    unsigned base = (unsigned)((lr * NCQ + lc) << 8);
    unsigned m    = ((unsigned)lc & 7u) << 4;
    offL = base + (((unsigned)g16) ^ m);
    offH = base + (((unsigned)(64 + g16)) ^ m);
}

template<int DX, int DY>   // corner tap: 4 points
__device__ __forceinline__ void geoC(float s1, float s2, int i, int j0, int lpx,
        int g16, unsigned oL[4], unsigned oH[4], float gw[4])
{
    int r0, r1, c0, c1; float wx0, wx1, wy0, wy1;
    axis_pts<DX>(s1, i + 1,        i - 2,  r0, r1, wx0, wx1);
    axis_pts<DY>(s2, j0 + lpx + 1, j0 - 2, c0, c1, wy0, wy1);
    mkpt(r0, c0, g16, oL[0], oH[0]);  gw[0] = wx0 * wy0;
    mkpt(r0, c1, g16, oL[1], oH[1]);  gw[1] = wx0 * wy1;
    mkpt(r1, c0, g16, oL[2], oH[2]);  gw[2] = wx1 * wy0;
    mkpt(r1, c1, g16, oL[3], oH[3]);  gw[3] = wx1 * wy1;
}

template<int DX, int DY>   // edge tap (one of DX,DY zero): 2 points
__device__ __forceinline__ void geoE(float s1, float s2, int i, int j0, int lpx,
        int g16, unsigned oL[2], unsigned oH[2], float gw[2])
{
    if (DX == 0) {
        int c0, c1; float wy0, wy1;
        axis_pts<DY>(s2, j0 + lpx + 1, j0 - 2, c0, c1, wy0, wy1);
        mkpt(2, c0, g16, oL[0], oH[0]);  gw[0] = wy0;
        mkpt(2, c1, g16, oL[1], oH[1]);  gw[1] = wy1;
    } else {
        int r0, r1; float wx0, wx1;
        axis_pts<DX>(s1, i + 1, i - 2, r0, r1, wx0, wx1);
        mkpt(r0, lpx + 2, g16, oL[0], oH[0]);  gw[0] = wx0;
        mkpt(r1, lpx + 2, g16, oL[1], oH[1]);  gw[1] = wx1;
    }
}

__device__ __forceinline__ f32x2 asf2(unsigned a, unsigned b) {
    f32x2 r; r.x = __uint_as_float(a); r.y = __uint_as_float(b); return r;
}

// split-tile tap accumulate: LQ/HQ dwords are ALREADY f32-formatted bf16
// values (lo<<16 / hi&FFFF0000 done at staging) -> feed v_pk_fma directly.
// Per channel the fma chain is op-identical to r6's fma16 -> bit-identical.
__device__ __forceinline__ void fma8s(uint4 LQ, uint4 HQ, f32x2 g2,
                                      f32x2* E, f32x2* O) {
    E[0] = __builtin_elementwise_fma(g2, asf2(LQ.x, LQ.y), E[0]);
    E[1] = __builtin_elementwise_fma(g2, asf2(LQ.z, LQ.w), E[1]);
    O[0] = __builtin_elementwise_fma(g2, asf2(HQ.x, HQ.y), O[0]);
    O[1] = __builtin_elementwise_fma(g2, asf2(HQ.z, HQ.w), O[1]);
}

// pack even/odd-channel accumulators back to channel-ordered bf16x8.
// Values are bitwise the same f32s as r6's v[2q]/v[2q+1] -> identical pack.
__device__ __forceinline__ bf16x8 packv2s(const f32x2* E, const f32x2* O) {
    uint4 p;
    p.x = pk2h(E[0].x, O[0].x); p.y = pk2h(E[0].y, O[0].y);
    p.z = pk2h(E[1].x, O[1].x); p.w = pk2h(E[1].y, O[1].y);
    union { uint4 u; bf16x8 b; } cv; cv.u = p;
    return cv.b;
}

// r6 structure + r3 staging split.  Change this round: LDS tile stored
// PRE-SPLIT (lo/hi planes, bf16 pre-positioned as f32) — removes the
// 192 unpack VALU ops/thread from the ds_read->pk_fma chains at the cost
// of 48 bit-ops at staging, 2x tile bytes, 2x ds traffic.
__global__ __launch_bounds__(256, 3) void ddconv_ws3(
    const unsigned short* __restrict__ xt, const float* __restrict__ alpha,
    const unsigned short* __restrict__ Wtb2, const float* __restrict__ bias,
    float* __restrict__ out)
{
    __shared__ __align__(16) char smem[46336];   // split tile 46080 + sincos 256; reduce reuses [0,40960)

    const int blk  = blockIdx.x;           // b*512 + i*4 + jq
    const int b    = blk >> 9;
    const int rem  = blk & 511;
    const int i    = rem >> 2;
    const int j0   = (rem & 3) << 5;
    const int t    = threadIdx.x;
    const int lane = t & 63;
    const int w    = t >> 6;
    const int llo  = lane & 15;
    const int g    = lane >> 4;
    const int g16  = g * 16;

    const char* xtb = (const char*)xt + (size_t)b * HW * 128;
    const char* wt2 = (const char*)Wtb2;
    const int arow  = llo * 64 + g16;

    // ---- stage 5 x 36 window: global burst (r3), then split-write ----
    char* tile = smem;
    uint4    sv[6];
    unsigned sla[6];
    {
        const char* sgp[6];
        #pragma unroll
        for (int k = 0; k < 6; ++k) {
            int q = t + k * 256;
            if (k == 5) q = min(q, NCHUNKQ - 1);     // clamp; write predicated
            int slot = q & 7;
            int rc   = q >> 3;
            int row  = rc / NCQ;
            int col  = rc - row * NCQ;
            int ru   = min(max(i - 2 + row, 0), 127);
            int cu   = min(max(j0 - 2 + col, 0), 127);
            sgp[k] = xtb + (size_t)(((ru << 7) + cu) << 7) + (slot << 4);
            sla[k] = ((unsigned)rc << 8) + (((unsigned)slot << 4) ^ (((unsigned)col & 7u) << 4));
        }
        #pragma unroll
        for (int k = 0; k < 6; ++k)
            sv[k] = *reinterpret_cast<const uint4*>(sgp[k]);
    }
    #pragma unroll
    for (int k = 0; k < 6; ++k) {
        if (k == 5 && t >= NCHUNKQ - 5 * 256) break;   // t < 160 writes k=5
        uint4 v = sv[k];
        uint4 lq, hq;
        lq.x = v.x << 16;          lq.y = v.y << 16;
        lq.z = v.z << 16;          lq.w = v.w << 16;
        hq.x = v.x & 0xFFFF0000u;  hq.y = v.y & 0xFFFF0000u;
        hq.z = v.z & 0xFFFF0000u;  hq.w = v.w & 0xFFFF0000u;
        *reinterpret_cast<uint4*>(tile + sla[k])       = lq;
        *reinterpret_cast<uint4*>(tile + sla[k] + 128) = hq;
    }

    // ---- per-wave A-fragment preload (validated r6; after staging loads) ----
    const int nn0 = (w==0)?0:(w==1)?2:(w==2)?6:8;
    const int nn1 = (w==0)?1:(w==1)?3:(w==2)?7:5;
    const int cs  = w >> 1;
    bf16x8 Ata[2][4], Atb[2][4], Ac0, Ac1;
    #pragma unroll
    for (int s = 0; s < 2; ++s)
      #pragma unroll
      for (int ot = 0; ot < 4; ++ot) {
        Ata[s][ot] = *reinterpret_cast<const bf16x8*>(wt2 + (nn0*2+s)*4096 + ot*1024 + arow);
        Atb[s][ot] = *reinterpret_cast<const bf16x8*>(wt2 + (nn1*2+s)*4096 + ot*1024 + arow);
      }
    Ac0 = *reinterpret_cast<const bf16x8*>(wt2 + (8+cs)*4096 + ((w&1)*2  )*1024 + arow);
    Ac1 = *reinterpret_cast<const bf16x8*>(wt2 + (8+cs)*4096 + ((w&1)*2+1)*1024 + arow);

    // ---- rotation: sincosf once per pixel on wave 0, broadcast via LDS ----
    float* sAB = reinterpret_cast<float*>(smem + TILE_BYTES);  // 64 floats
    if (t < 32) {
        float a = alpha[(b * Hn + i) * Wn + j0 + t];
        float sa, ca;
        sincosf(a, &sa, &ca);
        sAB[t]      = ca + sa;   // S1
        sAB[32 + t] = ca - sa;   // S2
    }

    f32x4 acc[2][4];
    #pragma unroll
    for (int pg = 0; pg < 2; ++pg)
      #pragma unroll
      for (int ot = 0; ot < 4; ++ot) acc[pg][ot] = (f32x4){0.f, 0.f, 0.f, 0.f};

    __syncthreads();

    float S1[2], S2[2];
    #pragma unroll
    for (int pg = 0; pg < 2; ++pg) {
        S1[pg] = sAB[pg * 16 + llo];
        S2[pg] = sAB[32 + pg * 16 + llo];
    }

    #define LDT(o) (*reinterpret_cast<const uint4*>(tile + (o)))

    #pragma unroll
    for (int pg = 0; pg < 2; ++pg) {
        const int lpx = pg * 16 + llo;

        // -- geometry: all addresses + weights precomputed --
        unsigned AL[4], AH[4], BL[2], BH[2];
        float    AG[4], BG[2];
        if (w == 0) {
            geoC<-1,-1>(S1[pg], S2[pg], i, j0, lpx, g16, AL, AH, AG);
            geoE<-1, 0>(S1[pg], S2[pg], i, j0, lpx, g16, BL, BH, BG);
        } else if (w == 1) {
            geoC<-1, 1>(S1[pg], S2[pg], i, j0, lpx, g16, AL, AH, AG);
            geoE< 0,-1>(S1[pg], S2[pg], i, j0, lpx, g16, BL, BH, BG);
        } else if (w == 2) {
            geoC< 1,-1>(S1[pg], S2[pg], i, j0, lpx, g16, AL, AH, AG);
            geoE< 1, 0>(S1[pg], S2[pg], i, j0, lpx, g16, BL, BH, BG);
        } else {
            geoC< 1, 1>(S1[pg], S2[pg], i, j0, lpx, g16, AL, AH, AG);
            geoE< 0, 1>(S1[pg], S2[pg], i, j0, lpx, g16, BL, BH, BG);
        }
        unsigned cb    = (unsigned)((2 * NCQ + lpx + 2) << 8);
        unsigned cm    = ((unsigned)(lpx + 2) & 7u) << 4;
        unsigned cAddr = cb + ((cs ? (unsigned)(64 + g16) : (unsigned)g16) ^ cm);

        // -- accumulators: even/odd channel pairs, L(v*) and H(w*) slices --
        f32x2 vE[2], vO[2], wE[2], wO[2];
        #pragma unroll
        for (int q = 0; q < 2; ++q) {
            vE[q] = (f32x2){0.f,0.f}; vO[q] = (f32x2){0.f,0.f};
            wE[q] = (f32x2){0.f,0.f}; wO[q] = (f32x2){0.f,0.f};
        }

        // -- corner taps: 1-ahead pipelined reads (4 x b128 per tap) --
        uint4 tl0 = LDT(AL[0]), th0 = LDT(AL[0] + 128);
        uint4 tl1 = LDT(AH[0]), th1 = LDT(AH[0] + 128);
        #pragma unroll
        for (int p = 0; p < 4; ++p) {
            uint4 nl0, nh0, nl1, nh1;
            if (p < 3) {
                nl0 = LDT(AL[p+1]); nh0 = LDT(AL[p+1] + 128);
                nl1 = LDT(AH[p+1]); nh1 = LDT(AH[p+1] + 128);
            }
            f32x2 g2; g2.x = AG[p]; g2.y = AG[p];
            fma8s(tl0, th0, g2, vE, vO);
            fma8s(tl1, th1, g2, wE, wO);
            if (p < 3) { tl0 = nl0; th0 = nh0; tl1 = nl1; th1 = nh1; }
        }
        bf16x8 bA0 = packv2s(vE, vO), bA1 = packv2s(wE, wO);

        // -- edge taps (2 points) --
        f32x2 uE[2], uO[2], tE[2], tO[2];
        #pragma unroll
        for (int q = 0; q < 2; ++q) {
            uE[q] = (f32x2){0.f,0.f}; uO[q] = (f32x2){0.f,0.f};
            tE[q] = (f32x2){0.f,0.f}; tO[q] = (f32x2){0.f,0.f};
        }
        {
            uint4 el0 = LDT(BL[0]), eh0 = LDT(BL[0] + 128);
            uint4 el1 = LDT(BH[0]), eh1 = LDT(BH[0] + 128);
            uint4 fl0 = LDT(BL[1]), fh0 = LDT(BL[1] + 128);
            uint4 fl1 = LDT(BH[1]), fh1 = LDT(BH[1] + 128);
            f32x2 g2; g2.x = BG[0]; g2.y = BG[0];
            fma8s(el0, eh0, g2, uE, uO);
            fma8s(el1, eh1, g2, tE, tO);
            g2.x = BG[1]; g2.y = BG[1];
            fma8s(fl0, fh0, g2, uE, uO);
            fma8s(fl1, fh1, g2, tE, tO);
        }
        bf16x8 bB0 = packv2s(uE, uO), bB1 = packv2s(tE, tO);

        // -- center tap: repack split planes to channel order (4 v_perm) --
        bf16x8 bc;
        {
            uint4 cl = LDT(cAddr), ch = LDT(cAddr + 128);
            uint4 cp;
            cp.x = __builtin_amdgcn_perm(ch.x, cl.x, 0x07060302u);
            cp.y = __builtin_amdgcn_perm(ch.y, cl.y, 0x07060302u);
            cp.z = __builtin_amdgcn_perm(ch.z, cl.z, 0x07060302u);
            cp.w = __builtin_amdgcn_perm(ch.w, cl.w, 0x07060302u);
            union { uint4 u; bf16x8 b; } cv; cv.u = cp;
            bc = cv.b;
        }

        #pragma unroll
        for (int ot = 0; ot < 4; ++ot) {
            acc[pg][ot] = __builtin_amdgcn_mfma_f32_16x16x32_bf16(Ata[0][ot], bA0, acc[pg][ot], 0, 0, 0);
            acc[pg][ot] = __builtin_amdgcn_mfma_f32_16x16x32_bf16(Ata[1][ot], bA1, acc[pg][ot], 0, 0, 0);
            acc[pg][ot] = __builtin_amdgcn_mfma_f32_16x16x32_bf16(Atb[0][ot], bB0, acc[pg][ot], 0, 0, 0);
            acc[pg][ot] = __builtin_amdgcn_mfma_f32_16x16x32_bf16(Atb[1][ot], bB1, acc[pg][ot], 0, 0, 0);
        }
        if (w & 1) {
            acc[pg][2] = __builtin_amdgcn_mfma_f32_16x16x32_bf16(Ac0, bc, acc[pg][2], 0, 0, 0);
            acc[pg][3] = __builtin_amdgcn_mfma_f32_16x16x32_bf16(Ac1, bc, acc[pg][3], 0, 0, 0);
        } else {
            acc[pg][0] = __builtin_amdgcn_mfma_f32_16x16x32_bf16(Ac0, bc, acc[pg][0], 0, 0, 0);
            acc[pg][1] = __builtin_amdgcn_mfma_f32_16x16x32_bf16(Ac1, bc, acc[pg][1], 0, 0, 0);
        }
    }
    #undef LDT

    // ---- cross-wave K-reduce through LDS (validated r4/r6) ----
    __syncthreads();
    #pragma unroll
    for (int pg = 0; pg < 2; ++pg)
      #pragma unroll
      for (int ot = 0; ot < 4; ++ot)
        *reinterpret_cast<f32x4*>(smem + ((pg*256 + w*64 + lane)*80) + ot*16) = acc[pg][ot];
    __syncthreads();
    {
        const int eq = w;
        #pragma unroll
        for (int pg = 0; pg < 2; ++pg) {
            f32x4 s = (f32x4){0.f, 0.f, 0.f, 0.f};
            #pragma unroll
            for (int ww = 0; ww < 4; ++ww)
                s += *reinterpret_cast<const f32x4*>(smem + ((pg*256 + ww*64 + lane)*80) + eq*16);
            int jj = j0 + pg * 16 + llo;
            float* ob = out + (size_t)b * COUT * HW + (size_t)i * Wn + jj;
            #pragma unroll
            for (int r = 0; r < 4; ++r) {
                int o = eq * 16 + g * 4 + r;
                ob[(size_t)o * HW] = s[r] + bias[o];
            }
        }
    }
}

// ====================== FALLBACK PATH (round-2, validated) ==================

__global__ void prep_weights(const float* __restrict__ weight,
                             unsigned short* __restrict__ Wtb) {
    int e = blockIdx.x * 256 + threadIdx.x;
    if (e >= COUT * KDIM) return;
    int o = e / KDIM, k = e % KDIM;
    int n = k >> 6, c = k & 63;
    int u = n % 3, v = n / 3;
    float w0 = weight[((o * CIN + c) * 3 + 0) * 3 + v];
    float w2 = weight[((o * CIN + c) * 3 + 2) * 3 + v];
    float val = (u == 0) ? w0 : ((u == 1) ? (-w0 - w2) : w2);
    Wtb[o * KDIM + k] = f2bf(val);
}

template<int DX, int DY>
__device__ __forceinline__ void gatherG(const float* __restrict__ xb,
    float s1, float s2, int i, int jj, int klocal,
    char* myrow, unsigned swz, int c0s, int c1s)
{
    int ix0 = 0, ix1 = 0; float wx0 = 1.f, wx1 = 0.f;
    if (DX != 0) {
        float px = (float)DX * s1 + (float)(i + 1);
        float fx = floorf(px);
        float qx0 = fminf(fmaxf(fx, 0.f), 129.f);
        float qx1 = fminf(fmaxf(fx + 1.f, 0.f), 129.f);
        wx0 = 1.f + (qx0 - px); wx1 = 1.f - (qx1 - px);
        ix0 = (int)qx0; ix1 = (int)qx1;
    } else { ix0 = i + 1; }
    int iy0 = 0, iy1 = 0; float wy0 = 1.f, wy1 = 0.f;
    if (DY != 0) {
        float py = (float)DY * s2 + (float)(jj + 1);
        float fy = floorf(py);
        float qy0 = fminf(fmaxf(fy, 0.f), 129.f);
        float qy1 = fminf(fmaxf(fy + 1.f, 0.f), 129.f);
        wy0 = 1.f + (qy0 - py); wy1 = 1.f - (qy1 - py);
        iy0 = (int)qy0; iy1 = (int)qy1;
    } else { iy0 = jj + 1; }

    constexpr int NX = (DX ? 2 : 1), NY = (DY ? 2 : 1), NT = NX * NY;
    unsigned idx[NT]; float g[NT];
    const int   ixs[2] = { ix0, ix1 };  const float wxs[2] = { wx0, wx1 };
    const int   iys[2] = { iy0, iy1 };  const float wys[2] = { wy0, wy1 };
    #pragma unroll
    for (int xi = 0; xi < NX; ++xi)
      #pragma unroll
      for (int yi = 0; yi < NY; ++yi) {
        int ix = ixs[xi], iy = iys[yi];
        bool ok = (ix >= 1) && (ix <= Hn) && (iy >= 1) && (iy <= Wn);
        int cx = min(max(ix, 1), Hn) - 1;
        int cy = min(max(iy, 1), Wn) - 1;
        idx[xi * NY + yi] = (unsigned)(cx * Wn + cy);
        g[xi * NY + yi]   = ok ? wxs[xi] * wys[yi] : 0.f;
      }
    for (int c0 = c0s; c0 < c1s; c0 += 8) {
        float v[8];
        #pragma unroll
        for (int cc = 0; cc < 8; ++cc) {
            unsigned coff = (unsigned)(c0 + cc) * HW;
            float acc2 = 0.f;
            #pragma unroll
            for (int tp = 0; tp < NT; ++tp)
                acc2 = fmaf(g[tp], xb[coff + idx[tp]], acc2);
            v[cc] = acc2;
        }
        uint4 d;
        d.x = pk2(v[0], v[1]); d.y = pk2(v[2], v[3]);
        d.z = pk2(v[4], v[5]); d.w = pk2(v[6], v[7]);
        unsigned addr = (unsigned)(klocal + c0) * 2u;
        *reinterpret_cast<uint4*>(myrow + (addr ^ swz)) = d;
    }
}

template<int KS>
__device__ __forceinline__ void mfma_phase(const char* emap,
    const unsigned short* __restrict__ Wtb,
    int w, int lane, int passbyte, f32x4 acc[4])
{
    const int llo = lane & 15, lhi = lane >> 4;
    const unsigned prow = (unsigned)(w * 16 + llo);
    const unsigned psw  = (prow & 7u) << 4;
    const char* erow = emap + prow * EROW;
    const char* wtb  = (const char*)Wtb + passbyte + lhi * 16;
    #pragma unroll
    for (int s = 0; s < KS; ++s) {
        unsigned kb = (unsigned)(s * 64 + lhi * 16);
        bf16x8 bf = *reinterpret_cast<const bf16x8*>(erow + (kb ^ psw));
        #pragma unroll
        for (int ot = 0; ot < 4; ++ot) {
            const char* ap = wtb + (ot * 16 + llo) * WROW + s * 64;
            bf16x8 af = *reinterpret_cast<const bf16x8*>(ap);
            acc[ot] = __builtin_amdgcn_mfma_f32_16x16x32_bf16(af, bf, acc[ot], 0, 0, 0);
        }
    }
}

__global__ __launch_bounds__(256, 3) void ddconv_mfma(
    const float* __restrict__ x, const float* __restrict__ alpha,
    const unsigned short* __restrict__ Wtb, const float* __restrict__ bias,
    float* __restrict__ out)
{
    __shared__ __align__(16) char emap[64 * EROW];
    const int blk  = blockIdx.x;
    const int b    = blk >> 8;
    const int rem  = blk & 255;
    const int i    = rem >> 1;
    const int j0   = (rem & 1) << 6;
    const int t    = threadIdx.x;
    const int lane = t & 63;
    const int w    = t >> 6;
    const int jj   = j0 + lane;
    const float* xb = x + (size_t)b * CIN * HW;
    float a = alpha[(b * Hn + i) * Wn + jj];
    float sa, ca;
    sincosf(a, &sa, &ca);
    const float s1 = ca + sa, s2 = ca - sa;
    char* myrow = emap + lane * EROW;
    const unsigned swz = (unsigned)((lane & 7) << 4);
    f32x4 acc[4];
    #pragma unroll
    for (int ot = 0; ot < 4; ++ot) acc[ot] = (f32x4){0.f, 0.f, 0.f, 0.f};
    if (w == 0)      { gatherG<-1,-1>(xb, s1, s2, i, jj,   0, myrow, swz,  0, 48); }
    else if (w == 1) { gatherG<-1,-1>(xb, s1, s2, i, jj,   0, myrow, swz, 48, 64);
                       gatherG<-1, 0>(xb, s1, s2, i, jj,  64, myrow, swz,  0, 64); }
    else if (w == 2) { gatherG<-1, 1>(xb, s1, s2, i, jj, 128, myrow, swz,  0, 48); }
    else             { gatherG<-1, 1>(xb, s1, s2, i, jj, 128, myrow, swz, 48, 64);
                       gatherG< 0,-1>(xb, s1, s2, i, jj, 192, myrow, swz,  0, 64); }
    __syncthreads();
    mfma_phase<8>(emap, Wtb, w, lane, 0, acc);
    __syncthreads();
    if (w == 0)      { gatherG< 1,-1>(xb, s1, s2, i, jj, 128, myrow, swz,  0, 56); }
    else if (w == 1) { gatherG< 1,-1>(xb, s1, s2, i, jj, 128, myrow, swz, 56, 64);
                       gatherG< 1, 1>(xb, s1, s2, i, jj, 256, myrow, swz,  0, 48); }
    else if (w == 2) { gatherG< 1, 1>(xb, s1, s2, i, jj, 256, myrow, swz, 48, 64);
                       gatherG< 0, 1>(xb, s1, s2, i, jj,  64, myrow, swz,  0, 64); }
    else             { gatherG< 1, 0>(xb, s1, s2, i, jj, 192, myrow, swz,  0, 64);
                       gatherG< 0, 0>(xb, s1, s2, i, jj,   0, myrow, swz,  0, 64); }
    __syncthreads();
    mfma_phase<10>(emap, Wtb, w, lane, 512, acc);
    const int llo = lane & 15, lhi = lane >> 4;
    float* ob = out + (size_t)b * COUT * HW + (size_t)i * Wn + j0 + w * 16 + llo;
    #pragma unroll
    for (int ot = 0; ot < 4; ++ot)
      #pragma unroll
      for (int r = 0; r < 4; ++r) {
        int o = ot * 16 + lhi * 4 + r;
        ob[(size_t)o * HW] = acc[ot][r] + bias[o];
      }
}

// ============================================================================

extern "C" void kernel_launch(void* const* d_in, const int* in_sizes, int n_in,
                              void* d_out, int out_size, void* d_ws, size_t ws_size,
                              hipStream_t stream) {
    const float* x      = (const float*)d_in[0];
    const float* alpha  = (const float*)d_in[1];
    const float* weight = (const float*)d_in[2];
    const float* bias   = (const float*)d_in[3];
    float* out = (float*)d_out;

    const size_t WT_BYTES = (size_t)COUT * KDIM * 2;          // 73728
    const size_t XT_BYTES = (size_t)4 * HW * CIN * 2;         // 8388608

    if (ws_size >= WT_BYTES + XT_BYTES) {
        unsigned short* Wtb2 = (unsigned short*)d_ws;
        unsigned short* xt   = (unsigned short*)((char*)d_ws + WT_BYTES);
        prep_fused<<<1168, 256, 0, stream>>>(x, weight, xt, Wtb2);
        ddconv_ws3<<<4 * Hn * (Wn / 32), 256, 0, stream>>>(xt, alpha, Wtb2, bias, out);
    } else {
        unsigned short* Wtb = (unsigned short*)d_ws;          // round-2 layout
        prep_weights<<<(COUT * KDIM + 255) / 256, 256, 0, stream>>>(weight, Wtb);
        ddconv_mfma<<<4 * Hn * (Wn / 64), 256, 0, stream>>>(x, alpha, Wtb, bias, out);
    }
}

// Round 5
// 32.410 us; speedup vs baseline: 1.1672x; 1.1672x over previous
//
#include <hip/hip_runtime.h>

#define CIN  64
#define COUT 64
#define Hn   128
#define Wn   128
#define HW   (Hn * Wn)
#define KDIM 576
#define WROW 1152   // fallback Wtb row stride in bytes
#define EROW 640    // fallback emap row stride in bytes

// r8 blocking: 2 rows x 16 cols per block -> 6 x 20 staged window
#define NRQ 6        // staged rows
#define NCQ 20       // staged cols
#define NCHUNKQ (NRQ * NCQ * 8)   // 16B chunks = 960
#define TILE_BYTES (NCHUNKQ * 16) // 15360

typedef __attribute__((ext_vector_type(8))) short bf16x8;
typedef __attribute__((ext_vector_type(4))) float f32x4;
typedef __attribute__((ext_vector_type(2))) float f32x2;

__device__ __forceinline__ unsigned short f2bf(float f) {
    unsigned u = __float_as_uint(f);
    unsigned r = u + 0x7FFFu + ((u >> 16) & 1u);   // RNE
    return (unsigned short)(r >> 16);
}
__device__ __forceinline__ unsigned pk2(float a, float b) {
    return (unsigned)f2bf(a) | ((unsigned)f2bf(b) << 16);
}
// half-up bf16 pair pack via v_perm (validated r2/r3, bit-identical).
__device__ __forceinline__ unsigned pk2h(float a, float b) {
    unsigned ua = __float_as_uint(a) + 0x8000u;
    unsigned ub = __float_as_uint(b) + 0x8000u;
    return __builtin_amdgcn_perm(ub, ua, 0x07060302u);
}

// ============================ FAST PATH =====================================

// Fused prep (r1/r3-validated): blocks [0,1024) transpose x; [1024,1168) Wtb2.
__global__ __launch_bounds__(256) void prep_fused(
    const float* __restrict__ x, const float* __restrict__ weight,
    unsigned short* __restrict__ xt, unsigned short* __restrict__ Wtb2)
{
    __shared__ float fbuf[64][65];
    if (blockIdx.x >= 1024) {
        int e = (blockIdx.x - 1024) * 256 + threadIdx.x;
        if (e < COUT * KDIM) {
            int o = e / KDIM, k = e % KDIM;
            int n = k >> 6, c = k & 63;
            int u = n % 3, v = n / 3;
            float w0 = weight[((o * CIN + c) * 3 + 0) * 3 + v];
            float w2 = weight[((o * CIN + c) * 3 + 2) * 3 + v];
            float val = (u == 0) ? w0 : ((u == 1) ? (-w0 - w2) : w2);
            int s = c >> 5;
            int ce = c & 31;
            Wtb2[((n * 2 + s) * 64 + o) * 32 + ce] = f2bf(val);
        }
        return;
    }
    const int blk = blockIdx.x;            // b*256 + h*2 + wtile
    const int b   = blk >> 8;
    const int rem = blk & 255;
    const int h   = rem >> 1;
    const int w0  = (rem & 1) << 6;
    const int t   = threadIdx.x;
    {
        int wq = t & 63, cq = t >> 6;
        const float* xp = x + ((size_t)(b * CIN + cq * 16) * Hn + h) * Wn + w0 + wq;
        #pragma unroll
        for (int r = 0; r < 16; ++r)
            fbuf[wq][cq * 16 + r] = xp[(size_t)r * HW];
    }
    __syncthreads();
    {
        int wq = t >> 2, q = t & 3;
        const float* row = &fbuf[wq][q * 16];
        uint4 d0, d1;
        d0.x = pk2(row[0],  row[1]);  d0.y = pk2(row[2],  row[3]);
        d0.z = pk2(row[4],  row[5]);  d0.w = pk2(row[6],  row[7]);
        d1.x = pk2(row[8],  row[9]);  d1.y = pk2(row[10], row[11]);
        d1.z = pk2(row[12], row[13]); d1.w = pk2(row[14], row[15]);
        unsigned short* op = xt + ((size_t)(b * Hn + h) * Wn + w0 + wq) * 64 + q * 16;
        *reinterpret_cast<uint4*>(op)     = d0;
        *reinterpret_cast<uint4*>(op + 8) = d1;
    }
}

// axis geometry (validated r5/r6): local tile indices + bilinear weights.
template<int D>
__device__ __forceinline__ void axis_pts(float s, int base1, int org,
                                         int& l0, int& l1, float& w0, float& w1)
{
    if (D) {
        float p  = (float)D * s + (float)base1;
        float f  = floorf(p);
        float q0 = fminf(fmaxf(f,       0.f), 129.f);
        float q1 = fminf(fmaxf(f + 1.f, 0.f), 129.f);
        w0 = 1.f + (q0 - p);  w1 = 1.f - (q1 - p);
        int i0 = (int)q0, i1 = (int)q1;
        if (i0 < 1 || i0 > 128) w0 = 0.f;
        if (i1 < 1 || i1 > 128) w1 = 0.f;
        l0 = min(max(i0 - 1, 0), 127) - org;
        l1 = min(max(i1 - 1, 0), 127) - org;
    } else {
        l0 = base1 - 1 - org;  w0 = 1.f;
        l1 = l0;               w1 = 0.f;
    }
}

// point -> two swizzled byte offsets (lo/hi 16-ch halves); NCQ=20 row stride.
__device__ __forceinline__ void mkpt(int lr, int lc, int g16,
                                     unsigned& offL, unsigned& offH) {
    unsigned base = (unsigned)((lr * NCQ + lc) << 7);
    unsigned m    = ((unsigned)lc & 7u) << 4;
    offL = base + (((unsigned)g16) ^ m);
    offH = base + (((unsigned)(64 + g16)) ^ m);
}

// corner tap: 4 points.  ipx/jpx = pixel row/col (global), iorg/jorg = window origin.
template<int DX, int DY>
__device__ __forceinline__ void geoC(float s1, float s2, int ipx, int iorg,
        int jpx, int jorg, int g16, unsigned oL[4], unsigned oH[4], float gw[4])
{
    int r0, r1, c0, c1; float wx0, wx1, wy0, wy1;
    axis_pts<DX>(s1, ipx + 1, iorg, r0, r1, wx0, wx1);
    axis_pts<DY>(s2, jpx + 1, jorg, c0, c1, wy0, wy1);
    mkpt(r0, c0, g16, oL[0], oH[0]);  gw[0] = wx0 * wy0;
    mkpt(r0, c1, g16, oL[1], oH[1]);  gw[1] = wx0 * wy1;
    mkpt(r1, c0, g16, oL[2], oH[2]);  gw[2] = wx1 * wy0;
    mkpt(r1, c1, g16, oL[3], oH[3]);  gw[3] = wx1 * wy1;
}

// edge tap (one of DX,DY zero): 2 points
template<int DX, int DY>
__device__ __forceinline__ void geoE(float s1, float s2, int ipx, int iorg,
        int jpx, int jorg, int g16, unsigned oL[2], unsigned oH[2], float gw[2])
{
    if (DX == 0) {
        int c0, c1; float wy0, wy1;
        axis_pts<DY>(s2, jpx + 1, jorg, c0, c1, wy0, wy1);
        mkpt(ipx - iorg, c0, g16, oL[0], oH[0]);  gw[0] = wy0;
        mkpt(ipx - iorg, c1, g16, oL[1], oH[1]);  gw[1] = wy1;
    } else {
        int r0, r1; float wx0, wx1;
        axis_pts<DX>(s1, ipx + 1, iorg, r0, r1, wx0, wx1);
        mkpt(r0, jpx - jorg, g16, oL[0], oH[0]);  gw[0] = wx0;
        mkpt(r1, jpx - jorg, g16, oL[1], oH[1]);  gw[1] = wx1;
    }
}

// bf16 pair -> f32x2 (lo<<16, hi&FFFF0000) — same bit patterns as r6's fma16.
__device__ __forceinline__ f32x2 bfpair(unsigned u) {
    f32x2 r;
    r.x = __uint_as_float(u << 16);
    r.y = __uint_as_float(u & 0xFFFF0000u);
    return r;
}

// packed-f32 version of r6's fma16: identical per-element fma chain.
__device__ __forceinline__ void fma16p(uint4 rl, uint4 rh, float gw,
                                       f32x2* v0, f32x2* v1) {
    const unsigned* u0 = reinterpret_cast<const unsigned*>(&rl);
    const unsigned* u1 = reinterpret_cast<const unsigned*>(&rh);
    f32x2 g2; g2.x = gw; g2.y = gw;
    #pragma unroll
    for (int q = 0; q < 4; ++q) {
        v0[q] = __builtin_elementwise_fma(g2, bfpair(u0[q]), v0[q]);
        v1[q] = __builtin_elementwise_fma(g2, bfpair(u1[q]), v1[q]);
    }
}

__device__ __forceinline__ bf16x8 packv2(const f32x2* v) {
    uint4 p;
    p.x = pk2h(v[0].x, v[0].y); p.y = pk2h(v[1].x, v[1].y);
    p.z = pk2h(v[2].x, v[2].y); p.w = pk2h(v[3].x, v[3].y);
    union { uint4 u; bf16x8 b; } cv; cv.u = p;
    return cv.b;
}

// r3 structure (validated: 36.4us) with 2x16 blocking this round:
// 32 px/block = 2 rows x 16 cols (pg indexes row), staged window 6x20=120 px
// (was 5x36=180): staging iterations 6->4, stage bytes -33%, tap math and
// all fp chains unchanged (bit-identical output).  r4's split tile reverted
// (2x LDS traffic regressed).
__global__ __launch_bounds__(256, 3) void ddconv_ws3(
    const unsigned short* __restrict__ xt, const float* __restrict__ alpha,
    const unsigned short* __restrict__ Wtb2, const float* __restrict__ bias,
    float* __restrict__ out)
{
    __shared__ __align__(16) char smem[40960];   // tile 15360 + sincos 256; reduce reuses 40960

    const int blk  = blockIdx.x;           // b*512 + (i0/2)*8 + (j0/16)
    const int b    = blk >> 9;
    const int rem  = blk & 511;
    const int i0   = (rem >> 3) << 1;
    const int j0   = (rem & 7) << 4;
    const int t    = threadIdx.x;
    const int lane = t & 63;
    const int w    = t >> 6;
    const int llo  = lane & 15;
    const int g    = lane >> 4;
    const int g16  = g * 16;
    const int iorg = i0 - 2, jorg = j0 - 2;

    const char* xtb = (const char*)xt + (size_t)b * HW * 128;
    const char* wt2 = (const char*)Wtb2;
    const int arow  = llo * 64 + g16;

    // ---- stage 6 x 20 window of xt, XOR-swizzled, load/write split (r3) ----
    char* tile = smem;
    uint4    sv[4];
    unsigned sla[4];
    {
        const char* sgp[4];
        #pragma unroll
        for (int k = 0; k < 4; ++k) {
            int q = t + k * 256;
            if (k == 3) q = min(q, NCHUNKQ - 1);     // clamp; write predicated
            int slot = q & 7;
            int rc   = q >> 3;
            int row  = rc / NCQ;
            int col  = rc - row * NCQ;
            int ru   = min(max(iorg + row, 0), 127);
            int cu   = min(max(jorg + col, 0), 127);
            sgp[k] = xtb + (size_t)(((ru << 7) + cu) << 7) + (slot << 4);
            sla[k] = ((unsigned)rc << 7) + (((unsigned)slot << 4) ^ (((unsigned)col & 7u) << 4));
        }
        #pragma unroll
        for (int k = 0; k < 4; ++k)
            sv[k] = *reinterpret_cast<const uint4*>(sgp[k]);
    }
    #pragma unroll
    for (int k = 0; k < 3; ++k)
        *reinterpret_cast<uint4*>(tile + sla[k]) = sv[k];
    if (t < NCHUNKQ - 3 * 256)   // t < 192
        *reinterpret_cast<uint4*>(tile + sla[3]) = sv[3];

    // ---- per-wave A-fragment preload (validated r6; after staging loads) ----
    const int nn0 = (w==0)?0:(w==1)?2:(w==2)?6:8;
    const int nn1 = (w==0)?1:(w==1)?3:(w==2)?7:5;
    const int cs  = w >> 1;
    bf16x8 Ata[2][4], Atb[2][4], Ac0, Ac1;
    #pragma unroll
    for (int s = 0; s < 2; ++s)
      #pragma unroll
      for (int ot = 0; ot < 4; ++ot) {
        Ata[s][ot] = *reinterpret_cast<const bf16x8*>(wt2 + (nn0*2+s)*4096 + ot*1024 + arow);
        Atb[s][ot] = *reinterpret_cast<const bf16x8*>(wt2 + (nn1*2+s)*4096 + ot*1024 + arow);
      }
    Ac0 = *reinterpret_cast<const bf16x8*>(wt2 + (8+cs)*4096 + ((w&1)*2  )*1024 + arow);
    Ac1 = *reinterpret_cast<const bf16x8*>(wt2 + (8+cs)*4096 + ((w&1)*2+1)*1024 + arow);

    // ---- rotation: sincosf once per pixel on wave 0, broadcast via LDS ----
    // pixel t: row i0 + (t>>4), col j0 + (t&15)  -> consumer sAB[pg*16+llo]
    float* sAB = reinterpret_cast<float*>(smem + TILE_BYTES);  // 64 floats
    if (t < 32) {
        float a = alpha[(b * Hn + i0 + (t >> 4)) * Wn + j0 + (t & 15)];
        float sa, ca;
        sincosf(a, &sa, &ca);
        sAB[t]      = ca + sa;   // S1
        sAB[32 + t] = ca - sa;   // S2
    }

    f32x4 acc[2][4];
    #pragma unroll
    for (int pg = 0; pg < 2; ++pg)
      #pragma unroll
      for (int ot = 0; ot < 4; ++ot) acc[pg][ot] = (f32x4){0.f, 0.f, 0.f, 0.f};

    __syncthreads();

    float S1[2], S2[2];
    #pragma unroll
    for (int pg = 0; pg < 2; ++pg) {
        S1[pg] = sAB[pg * 16 + llo];
        S2[pg] = sAB[32 + pg * 16 + llo];
    }

    #pragma unroll
    for (int pg = 0; pg < 2; ++pg) {
        const int ipx = i0 + pg;
        const int jpx = j0 + llo;

        // -- geometry: all addresses + weights precomputed --
        unsigned AL[4], AH[4], BL[2], BH[2];
        float    AG[4], BG[2];
        if (w == 0) {
            geoC<-1,-1>(S1[pg], S2[pg], ipx, iorg, jpx, jorg, g16, AL, AH, AG);
            geoE<-1, 0>(S1[pg], S2[pg], ipx, iorg, jpx, jorg, g16, BL, BH, BG);
        } else if (w == 1) {
            geoC<-1, 1>(S1[pg], S2[pg], ipx, iorg, jpx, jorg, g16, AL, AH, AG);
            geoE< 0,-1>(S1[pg], S2[pg], ipx, iorg, jpx, jorg, g16, BL, BH, BG);
        } else if (w == 2) {
            geoC< 1,-1>(S1[pg], S2[pg], ipx, iorg, jpx, jorg, g16, AL, AH, AG);
            geoE< 1, 0>(S1[pg], S2[pg], ipx, iorg, jpx, jorg, g16, BL, BH, BG);
        } else {
            geoC< 1, 1>(S1[pg], S2[pg], ipx, iorg, jpx, jorg, g16, AL, AH, AG);
            geoE< 0, 1>(S1[pg], S2[pg], ipx, iorg, jpx, jorg, g16, BL, BH, BG);
        }
        const int lcc  = jpx - jorg;          // llo + 2
        unsigned cb    = (unsigned)((((ipx - iorg) * NCQ) + lcc) << 7);
        unsigned cm    = ((unsigned)lcc & 7u) << 4;
        unsigned cAddr = cb + ((cs ? (unsigned)(64 + g16) : (unsigned)g16) ^ cm);

        // -- hoisted load burst: 13 ds_read_b128 back-to-back --
        uint4 La[4], Ha[4];
        #pragma unroll
        for (int p = 0; p < 4; ++p) {
            La[p] = *reinterpret_cast<const uint4*>(tile + AL[p]);
            Ha[p] = *reinterpret_cast<const uint4*>(tile + AH[p]);
        }
        uint4 Lb[2], Hb[2];
        #pragma unroll
        for (int p = 0; p < 2; ++p) {
            Lb[p] = *reinterpret_cast<const uint4*>(tile + BL[p]);
            Hb[p] = *reinterpret_cast<const uint4*>(tile + BH[p]);
        }
        bf16x8 bc = *reinterpret_cast<const bf16x8*>(tile + cAddr);

        // -- consume (same fp element order as r6, packed 2-wide) --
        f32x2 v0[4], v1[4];
        #pragma unroll
        for (int q = 0; q < 4; ++q) { v0[q] = (f32x2){0.f,0.f}; v1[q] = (f32x2){0.f,0.f}; }
        #pragma unroll
        for (int p = 0; p < 4; ++p) fma16p(La[p], Ha[p], AG[p], v0, v1);
        bf16x8 bA0 = packv2(v0), bA1 = packv2(v1);

        f32x2 u0[4], u1[4];
        #pragma unroll
        for (int q = 0; q < 4; ++q) { u0[q] = (f32x2){0.f,0.f}; u1[q] = (f32x2){0.f,0.f}; }
        #pragma unroll
        for (int p = 0; p < 2; ++p) fma16p(Lb[p], Hb[p], BG[p], u0, u1);
        bf16x8 bB0 = packv2(u0), bB1 = packv2(u1);

        #pragma unroll
        for (int ot = 0; ot < 4; ++ot) {
            acc[pg][ot] = __builtin_amdgcn_mfma_f32_16x16x32_bf16(Ata[0][ot], bA0, acc[pg][ot], 0, 0, 0);
            acc[pg][ot] = __builtin_amdgcn_mfma_f32_16x16x32_bf16(Ata[1][ot], bA1, acc[pg][ot], 0, 0, 0);
            acc[pg][ot] = __builtin_amdgcn_mfma_f32_16x16x32_bf16(Atb[0][ot], bB0, acc[pg][ot], 0, 0, 0);
            acc[pg][ot] = __builtin_amdgcn_mfma_f32_16x16x32_bf16(Atb[1][ot], bB1, acc[pg][ot], 0, 0, 0);
        }
        if (w & 1) {
            acc[pg][2] = __builtin_amdgcn_mfma_f32_16x16x32_bf16(Ac0, bc, acc[pg][2], 0, 0, 0);
            acc[pg][3] = __builtin_amdgcn_mfma_f32_16x16x32_bf16(Ac1, bc, acc[pg][3], 0, 0, 0);
        } else {
            acc[pg][0] = __builtin_amdgcn_mfma_f32_16x16x32_bf16(Ac0, bc, acc[pg][0], 0, 0, 0);
            acc[pg][1] = __builtin_amdgcn_mfma_f32_16x16x32_bf16(Ac1, bc, acc[pg][1], 0, 0, 0);
        }
    }

    // ---- cross-wave K-reduce through LDS (validated r4/r6) ----
    __syncthreads();
    #pragma unroll
    for (int pg = 0; pg < 2; ++pg)
      #pragma unroll
      for (int ot = 0; ot < 4; ++ot)
        *reinterpret_cast<f32x4*>(smem + ((pg*256 + w*64 + lane)*80) + ot*16) = acc[pg][ot];
    __syncthreads();
    {
        const int eq = w;
        #pragma unroll
        for (int pg = 0; pg < 2; ++pg) {
            f32x4 s = (f32x4){0.f, 0.f, 0.f, 0.f};
            #pragma unroll
            for (int ww = 0; ww < 4; ++ww)
                s += *reinterpret_cast<const f32x4*>(smem + ((pg*256 + ww*64 + lane)*80) + eq*16);
            float* ob = out + (size_t)b * COUT * HW + (size_t)(i0 + pg) * Wn + j0 + llo;
            #pragma unroll
            for (int r = 0; r < 4; ++r) {
                int o = eq * 16 + g * 4 + r;
                ob[(size_t)o * HW] = s[r] + bias[o];
            }
        }
    }
}

// ====================== FALLBACK PATH (round-2, validated) ==================

__global__ void prep_weights(const float* __restrict__ weight,
                             unsigned short* __restrict__ Wtb) {
    int e = blockIdx.x * 256 + threadIdx.x;
    if (e >= COUT * KDIM) return;
    int o = e / KDIM, k = e % KDIM;
    int n = k >> 6, c = k & 63;
    int u = n % 3, v = n / 3;
    float w0 = weight[((o * CIN + c) * 3 + 0) * 3 + v];
    float w2 = weight[((o * CIN + c) * 3 + 2) * 3 + v];
    float val = (u == 0) ? w0 : ((u == 1) ? (-w0 - w2) : w2);
    Wtb[o * KDIM + k] = f2bf(val);
}

template<int DX, int DY>
__device__ __forceinline__ void gatherG(const float* __restrict__ xb,
    float s1, float s2, int i, int jj, int klocal,
    char* myrow, unsigned swz, int c0s, int c1s)
{
    int ix0 = 0, ix1 = 0; float wx0 = 1.f, wx1 = 0.f;
    if (DX != 0) {
        float px = (float)DX * s1 + (float)(i + 1);
        float fx = floorf(px);
        float qx0 = fminf(fmaxf(fx, 0.f), 129.f);
        float qx1 = fminf(fmaxf(fx + 1.f, 0.f), 129.f);
        wx0 = 1.f + (qx0 - px); wx1 = 1.f - (qx1 - px);
        ix0 = (int)qx0; ix1 = (int)qx1;
    } else { ix0 = i + 1; }
    int iy0 = 0, iy1 = 0; float wy0 = 1.f, wy1 = 0.f;
    if (DY != 0) {
        float py = (float)DY * s2 + (float)(jj + 1);
        float fy = floorf(py);
        float qy0 = fminf(fmaxf(fy, 0.f), 129.f);
        float qy1 = fminf(fmaxf(fy + 1.f, 0.f), 129.f);
        wy0 = 1.f + (qy0 - py); wy1 = 1.f - (qy1 - py);
        iy0 = (int)qy0; iy1 = (int)qy1;
    } else { iy0 = jj + 1; }

    constexpr int NX = (DX ? 2 : 1), NY = (DY ? 2 : 1), NT = NX * NY;
    unsigned idx[NT]; float g[NT];
    const int   ixs[2] = { ix0, ix1 };  const float wxs[2] = { wx0, wx1 };
    const int   iys[2] = { iy0, iy1 };  const float wys[2] = { wy0, wy1 };
    #pragma unroll
    for (int xi = 0; xi < NX; ++xi)
      #pragma unroll
      for (int yi = 0; yi < NY; ++yi) {
        int ix = ixs[xi], iy = iys[yi];
        bool ok = (ix >= 1) && (ix <= Hn) && (iy >= 1) && (iy <= Wn);
        int cx = min(max(ix, 1), Hn) - 1;
        int cy = min(max(iy, 1), Wn) - 1;
        idx[xi * NY + yi] = (unsigned)(cx * Wn + cy);
        g[xi * NY + yi]   = ok ? wxs[xi] * wys[yi] : 0.f;
      }
    for (int c0 = c0s; c0 < c1s; c0 += 8) {
        float v[8];
        #pragma unroll
        for (int cc = 0; cc < 8; ++cc) {
            unsigned coff = (unsigned)(c0 + cc) * HW;
            float acc2 = 0.f;
            #pragma unroll
            for (int tp = 0; tp < NT; ++tp)
                acc2 = fmaf(g[tp], xb[coff + idx[tp]], acc2);
            v[cc] = acc2;
        }
        uint4 d;
        d.x = pk2(v[0], v[1]); d.y = pk2(v[2], v[3]);
        d.z = pk2(v[4], v[5]); d.w = pk2(v[6], v[7]);
        unsigned addr = (unsigned)(klocal + c0) * 2u;
        *reinterpret_cast<uint4*>(myrow + (addr ^ swz)) = d;
    }
}

template<int KS>
__device__ __forceinline__ void mfma_phase(const char* emap,
    const unsigned short* __restrict__ Wtb,
    int w, int lane, int passbyte, f32x4 acc[4])
{
    const int llo = lane & 15, lhi = lane >> 4;
    const unsigned prow = (unsigned)(w * 16 + llo);
    const unsigned psw  = (prow & 7u) << 4;
    const char* erow = emap + prow * EROW;
    const char* wtb  = (const char*)Wtb + passbyte + lhi * 16;
    #pragma unroll
    for (int s = 0; s < KS; ++s) {
        unsigned kb = (unsigned)(s * 64 + lhi * 16);
        bf16x8 bf = *reinterpret_cast<const bf16x8*>(erow + (kb ^ psw));
        #pragma unroll
        for (int ot = 0; ot < 4; ++ot) {
            const char* ap = wtb + (ot * 16 + llo) * WROW + s * 64;
            bf16x8 af = *reinterpret_cast<const bf16x8*>(ap);
            acc[ot] = __builtin_amdgcn_mfma_f32_16x16x32_bf16(af, bf, acc[ot], 0, 0, 0);
        }
    }
}

__global__ __launch_bounds__(256, 3) void ddconv_mfma(
    const float* __restrict__ x, const float* __restrict__ alpha,
    const unsigned short* __restrict__ Wtb, const float* __restrict__ bias,
    float* __restrict__ out)
{
    __shared__ __align__(16) char emap[64 * EROW];
    const int blk  = blockIdx.x;
    const int b    = blk >> 8;
    const int rem  = blk & 255;
    const int i    = rem >> 1;
    const int j0   = (rem & 1) << 6;
    const int t    = threadIdx.x;
    const int lane = t & 63;
    const int w    = t >> 6;
    const int jj   = j0 + lane;
    const float* xb = x + (size_t)b * CIN * HW;
    float a = alpha[(b * Hn + i) * Wn + jj];
    float sa, ca;
    sincosf(a, &sa, &ca);
    const float s1 = ca + sa, s2 = ca - sa;
    char* myrow = emap + lane * EROW;
    const unsigned swz = (unsigned)((lane & 7) << 4);
    f32x4 acc[4];
    #pragma unroll
    for (int ot = 0; ot < 4; ++ot) acc[ot] = (f32x4){0.f, 0.f, 0.f, 0.f};
    if (w == 0)      { gatherG<-1,-1>(xb, s1, s2, i, jj,   0, myrow, swz,  0, 48); }
    else if (w == 1) { gatherG<-1,-1>(xb, s1, s2, i, jj,   0, myrow, swz, 48, 64);
                       gatherG<-1, 0>(xb, s1, s2, i, jj,  64, myrow, swz,  0, 64); }
    else if (w == 2) { gatherG<-1, 1>(xb, s1, s2, i, jj, 128, myrow, swz,  0, 48); }
    else             { gatherG<-1, 1>(xb, s1, s2, i, jj, 128, myrow, swz, 48, 64);
                       gatherG< 0,-1>(xb, s1, s2, i, jj, 192, myrow, swz,  0, 64); }
    __syncthreads();
    mfma_phase<8>(emap, Wtb, w, lane, 0, acc);
    __syncthreads();
    if (w == 0)      { gatherG< 1,-1>(xb, s1, s2, i, jj, 128, myrow, swz,  0, 56); }
    else if (w == 1) { gatherG< 1,-1>(xb, s1, s2, i, jj, 128, myrow, swz, 56, 64);
                       gatherG< 1, 1>(xb, s1, s2, i, jj, 256, myrow, swz,  0, 48); }
    else if (w == 2) { gatherG< 1, 1>(xb, s1, s2, i, jj, 256, myrow, swz, 48, 64);
                       gatherG< 0, 1>(xb, s1, s2, i, jj,  64, myrow, swz,  0, 64); }
    else             { gatherG< 1, 0>(xb, s1, s2, i, jj, 192, myrow, swz,  0, 64);
                       gatherG< 0, 0>(xb, s1, s2, i, jj,   0, myrow, swz,  0, 64); }
    __syncthreads();
    mfma_phase<10>(emap, Wtb, w, lane, 512, acc);
    const int llo = lane & 15, lhi = lane >> 4;
    float* ob = out + (size_t)b * COUT * HW + (size_t)i * Wn + j0 + w * 16 + llo;
    #pragma unroll
    for (int ot = 0; ot < 4; ++ot)
      #pragma unroll
      for (int r = 0; r < 4; ++r) {
        int o = ot * 16 + lhi * 4 + r;
        ob[(size_t)o * HW] = acc[ot][r] + bias[o];
      }
}

// ============================================================================

extern "C" void kernel_launch(void* const* d_in, const int* in_sizes, int n_in,
                              void* d_out, int out_size, void* d_ws, size_t ws_size,
                              hipStream_t stream) {
    const float* x      = (const float*)d_in[0];
    const float* alpha  = (const float*)d_in[1];
    const float* weight = (const float*)d_in[2];
    const float* bias   = (const float*)d_in[3];
    float* out = (float*)d_out;

    const size_t WT_BYTES = (size_t)COUT * KDIM * 2;          // 73728
    const size_t XT_BYTES = (size_t)4 * HW * CIN * 2;         // 8388608

    if (ws_size >= WT_BYTES + XT_BYTES) {
        unsigned short* Wtb2 = (unsigned short*)d_ws;
        unsigned short* xt   = (unsigned short*)((char*)d_ws + WT_BYTES);
        prep_fused<<<1168, 256, 0, stream>>>(x, weight, xt, Wtb2);
        ddconv_ws3<<<4 * (Hn / 2) * (Wn / 16), 256, 0, stream>>>(xt, alpha, Wtb2, bias, out);
    } else {
        unsigned short* Wtb = (unsigned short*)d_ws;          // round-2 layout
        prep_weights<<<(COUT * KDIM + 255) / 256, 256, 0, stream>>>(weight, Wtb);
        ddconv_mfma<<<4 * Hn * (Wn / 64), 256, 0, stream>>>(x, alpha, Wtb, bias, out);
    }
}

// Round 6
// 31.928 us; speedup vs baseline: 1.1848x; 1.0151x over previous
//
#include <hip/hip_runtime.h>

#define CIN  64
#define COUT 64
#define Hn   128
#define Wn   128
#define HW   (Hn * Wn)
#define KDIM 576
#define WROW 1152   // fallback Wtb row stride in bytes
#define EROW 640    // fallback emap row stride in bytes

// 2 rows x 16 cols per block -> 6 x 20 staged window (validated r5)
#define NRQ 6        // staged rows
#define NCQ 20       // staged cols
#define NCHUNKQ (NRQ * NCQ * 8)   // 16B chunks = 960
#define PIXB 144     // r6: padded pixel stride (9x16B; 9 coprime 8 -> bank rotation, no XOR)
#define TILE_BYTES (NRQ * NCQ * PIXB)  // 17280

typedef __attribute__((ext_vector_type(8))) short bf16x8;
typedef __attribute__((ext_vector_type(4))) float f32x4;
typedef __attribute__((ext_vector_type(2))) float f32x2;

__device__ __forceinline__ unsigned short f2bf(float f) {
    unsigned u = __float_as_uint(f);
    unsigned r = u + 0x7FFFu + ((u >> 16) & 1u);   // RNE
    return (unsigned short)(r >> 16);
}
// r6: hardware packed f32->bf16 (RNE), 1 VALU op (guide T12: no builtin on gfx950).
// lo = cvt(a), hi = cvt(b).  RNE == f2bf bit-for-bit.
__device__ __forceinline__ unsigned pk2c(float a, float b) {
    unsigned r;
    asm("v_cvt_pk_bf16_f32 %0, %1, %2" : "=v"(r) : "v"(a), "v"(b));
    return r;
}

// ============================ FAST PATH =====================================

// Fused prep (r1/r3-validated): blocks [0,1024) transpose x; [1024,1168) Wtb2.
// r6: pk2 -> v_cvt_pk_bf16_f32 (bit-identical RNE, 9 ops -> 1).
__global__ __launch_bounds__(256) void prep_fused(
    const float* __restrict__ x, const float* __restrict__ weight,
    unsigned short* __restrict__ xt, unsigned short* __restrict__ Wtb2)
{
    __shared__ float fbuf[64][65];
    if (blockIdx.x >= 1024) {
        int e = (blockIdx.x - 1024) * 256 + threadIdx.x;
        if (e < COUT * KDIM) {
            int o = e / KDIM, k = e % KDIM;
            int n = k >> 6, c = k & 63;
            int u = n % 3, v = n / 3;
            float w0 = weight[((o * CIN + c) * 3 + 0) * 3 + v];
            float w2 = weight[((o * CIN + c) * 3 + 2) * 3 + v];
            float val = (u == 0) ? w0 : ((u == 1) ? (-w0 - w2) : w2);
            int s = c >> 5;
            int ce = c & 31;
            Wtb2[((n * 2 + s) * 64 + o) * 32 + ce] = f2bf(val);
        }
        return;
    }
    const int blk = blockIdx.x;            // b*256 + h*2 + wtile
    const int b   = blk >> 8;
    const int rem = blk & 255;
    const int h   = rem >> 1;
    const int w0  = (rem & 1) << 6;
    const int t   = threadIdx.x;
    {
        int wq = t & 63, cq = t >> 6;
        const float* xp = x + ((size_t)(b * CIN + cq * 16) * Hn + h) * Wn + w0 + wq;
        #pragma unroll
        for (int r = 0; r < 16; ++r)
            fbuf[wq][cq * 16 + r] = xp[(size_t)r * HW];
    }
    __syncthreads();
    {
        int wq = t >> 2, q = t & 3;
        const float* row = &fbuf[wq][q * 16];
        uint4 d0, d1;
        d0.x = pk2c(row[0],  row[1]);  d0.y = pk2c(row[2],  row[3]);
        d0.z = pk2c(row[4],  row[5]);  d0.w = pk2c(row[6],  row[7]);
        d1.x = pk2c(row[8],  row[9]);  d1.y = pk2c(row[10], row[11]);
        d1.z = pk2c(row[12], row[13]); d1.w = pk2c(row[14], row[15]);
        unsigned short* op = xt + ((size_t)(b * Hn + h) * Wn + w0 + wq) * 64 + q * 16;
        *reinterpret_cast<uint4*>(op)     = d0;
        *reinterpret_cast<uint4*>(op + 8) = d1;
    }
}

// axis geometry (validated r5/r6): local tile indices + bilinear weights.
template<int D>
__device__ __forceinline__ void axis_pts(float s, int base1, int org,
                                         int& l0, int& l1, float& w0, float& w1)
{
    float p  = (float)D * s + (float)base1;
    float f  = floorf(p);
    float q0 = fminf(fmaxf(f,       0.f), 129.f);
    float q1 = fminf(fmaxf(f + 1.f, 0.f), 129.f);
    w0 = 1.f + (q0 - p);  w1 = 1.f - (q1 - p);
    int i0 = (int)q0, i1 = (int)q1;
    if (i0 < 1 || i0 > 128) w0 = 0.f;
    if (i1 < 1 || i1 > 128) w1 = 0.f;
    l0 = min(max(i0 - 1, 0), 127) - org;
    l1 = min(max(i1 - 1, 0), 127) - org;
}

// pixel (lr,lc) -> L-half byte offset in the pad-144 tile (+g16 channel slot).
// H-half is +64 (ds_read offset immediate at the consumer).
__device__ __forceinline__ unsigned pixb(int lr, int lc, int g16) {
    return (unsigned)((lr * NCQ + lc) * PIXB + g16);
}

// r6: per-wave geometry with axis reuse.  Corner axes (DXc,DYc) are computed
// once; the edge tap reuses the matching corner axis (identical template args
// + inputs -> bit-identical) except w1 (EDY=-1 vs corner +1 -> extra axis).
template<int DXc, int DYc, int EDX, int EDY>
__device__ __forceinline__ void geoW(float s1, float s2, int ipx, int iorg,
        int jpx, int jorg, int g16, unsigned A[4], float AG[4],
        unsigned B[2], float BG[2])
{
    int r0, r1, c0, c1; float wx0, wx1, wy0, wy1;
    axis_pts<DXc>(s1, ipx + 1, iorg, r0, r1, wx0, wx1);
    axis_pts<DYc>(s2, jpx + 1, jorg, c0, c1, wy0, wy1);
    A[0] = pixb(r0, c0, g16);  AG[0] = wx0 * wy0;
    A[1] = pixb(r0, c1, g16);  AG[1] = wx0 * wy1;
    A[2] = pixb(r1, c0, g16);  AG[2] = wx1 * wy0;
    A[3] = pixb(r1, c1, g16);  AG[3] = wx1 * wy1;
    if (EDY == 0) {                    // w0, w2: reuse x-axis, fixed col
        int lc = jpx - jorg;
        B[0] = pixb(r0, lc, g16);  BG[0] = wx0;
        B[1] = pixb(r1, lc, g16);  BG[1] = wx1;
    } else if (EDY == DYc) {           // w3: reuse y-axis, fixed row
        int lr = ipx - iorg;
        B[0] = pixb(lr, c0, g16);  BG[0] = wy0;
        B[1] = pixb(lr, c1, g16);  BG[1] = wy1;
    } else {                           // w1: extra y-axis (EDY = -1)
        int e0, e1; float v0, v1;
        axis_pts<EDY>(s2, jpx + 1, jorg, e0, e1, v0, v1);
        int lr = ipx - iorg;
        B[0] = pixb(lr, e0, g16);  BG[0] = v0;
        B[1] = pixb(lr, e1, g16);  BG[1] = v1;
    }
}

// bf16 pair -> f32x2 (lo<<16, hi&FFFF0000) — same bit patterns as r6's fma16.
__device__ __forceinline__ f32x2 bfpair(unsigned u) {
    f32x2 r;
    r.x = __uint_as_float(u << 16);
    r.y = __uint_as_float(u & 0xFFFF0000u);
    return r;
}

// packed-f32 version of r6's fma16: identical per-element fma chain.
__device__ __forceinline__ void fma16p(uint4 rl, uint4 rh, float gw,
                                       f32x2* v0, f32x2* v1) {
    const unsigned* u0 = reinterpret_cast<const unsigned*>(&rl);
    const unsigned* u1 = reinterpret_cast<const unsigned*>(&rh);
    f32x2 g2; g2.x = gw; g2.y = gw;
    #pragma unroll
    for (int q = 0; q < 4; ++q) {
        v0[q] = __builtin_elementwise_fma(g2, bfpair(u0[q]), v0[q]);
        v1[q] = __builtin_elementwise_fma(g2, bfpair(u1[q]), v1[q]);
    }
}

__device__ __forceinline__ bf16x8 packv2(const f32x2* v) {
    uint4 p;
    p.x = pk2c(v[0].x, v[0].y); p.y = pk2c(v[1].x, v[1].y);
    p.z = pk2c(v[2].x, v[2].y); p.w = pk2c(v[3].x, v[3].y);
    union { uint4 u; bf16x8 b; } cv; cv.u = p;
    return cv.b;
}

// r5 structure (validated: 32.4us).  r6 changes:
//  (a) pad-144 tile (no XOR; H-half = L+64 ds offset immediate),
//  (b) geoW axis reuse for edge taps,
//  (c) v_cvt_pk_bf16_f32 packing (3 ops -> 1; RNE ties vs half-up).
__global__ __launch_bounds__(256, 3) void ddconv_ws3(
    const unsigned short* __restrict__ xt, const float* __restrict__ alpha,
    const unsigned short* __restrict__ Wtb2, const float* __restrict__ bias,
    float* __restrict__ out)
{
    __shared__ __align__(16) char smem[40960];   // tile 17280 + sincos 256; reduce reuses 40960

    const int blk  = blockIdx.x;           // b*512 + (i0/2)*8 + (j0/16)
    const int b    = blk >> 9;
    const int rem  = blk & 511;
    const int i0   = (rem >> 3) << 1;
    const int j0   = (rem & 7) << 4;
    const int t    = threadIdx.x;
    const int lane = t & 63;
    const int w    = t >> 6;
    const int llo  = lane & 15;
    const int g    = lane >> 4;
    const int g16  = g * 16;
    const int iorg = i0 - 2, jorg = j0 - 2;

    const char* xtb = (const char*)xt + (size_t)b * HW * 128;
    const char* wt2 = (const char*)Wtb2;
    const int arow  = llo * 64 + g16;

    // ---- stage 6 x 20 window of xt, pad-144, load/write split (r3/r5) ----
    char* tile = smem;
    uint4    sv[4];
    unsigned sla[4];
    {
        const char* sgp[4];
        const int slot16 = (t & 7) << 4;           // slot const across k (256%8==0)
        #pragma unroll
        for (int k = 0; k < 4; ++k) {
            int q = t + k * 256;
            if (k == 3) q = min(q, NCHUNKQ - 1);   // clamp; write predicated
            int rc   = q >> 3;
            int row  = rc / NCQ;
            int col  = rc - row * NCQ;
            int ru   = min(max(iorg + row, 0), 127);
            int cu   = min(max(jorg + col, 0), 127);
            sgp[k] = xtb + (size_t)(((ru << 7) + cu) << 7) + slot16;
            sla[k] = (unsigned)(rc * PIXB) + slot16;
        }
        #pragma unroll
        for (int k = 0; k < 4; ++k)
            sv[k] = *reinterpret_cast<const uint4*>(sgp[k]);
    }
    #pragma unroll
    for (int k = 0; k < 3; ++k)
        *reinterpret_cast<uint4*>(tile + sla[k]) = sv[k];
    if (t < NCHUNKQ - 3 * 256)   // t < 192
        *reinterpret_cast<uint4*>(tile + sla[3]) = sv[3];

    // ---- per-wave A-fragment preload (validated r6; after staging loads) ----
    const int nn0 = (w==0)?0:(w==1)?2:(w==2)?6:8;
    const int nn1 = (w==0)?1:(w==1)?3:(w==2)?7:5;
    const int cs  = w >> 1;
    bf16x8 Ata[2][4], Atb[2][4], Ac0, Ac1;
    #pragma unroll
    for (int s = 0; s < 2; ++s)
      #pragma unroll
      for (int ot = 0; ot < 4; ++ot) {
        Ata[s][ot] = *reinterpret_cast<const bf16x8*>(wt2 + (nn0*2+s)*4096 + ot*1024 + arow);
        Atb[s][ot] = *reinterpret_cast<const bf16x8*>(wt2 + (nn1*2+s)*4096 + ot*1024 + arow);
      }
    Ac0 = *reinterpret_cast<const bf16x8*>(wt2 + (8+cs)*4096 + ((w&1)*2  )*1024 + arow);
    Ac1 = *reinterpret_cast<const bf16x8*>(wt2 + (8+cs)*4096 + ((w&1)*2+1)*1024 + arow);

    // ---- rotation: sincosf once per pixel on wave 0, broadcast via LDS ----
    // pixel t: row i0 + (t>>4), col j0 + (t&15)  -> consumer sAB[pg*16+llo]
    float* sAB = reinterpret_cast<float*>(smem + TILE_BYTES);  // 64 floats
    if (t < 32) {
        float a = alpha[(b * Hn + i0 + (t >> 4)) * Wn + j0 + (t & 15)];
        float sa, ca;
        sincosf(a, &sa, &ca);
        sAB[t]      = ca + sa;   // S1
        sAB[32 + t] = ca - sa;   // S2
    }

    f32x4 acc[2][4];
    #pragma unroll
    for (int pg = 0; pg < 2; ++pg)
      #pragma unroll
      for (int ot = 0; ot < 4; ++ot) acc[pg][ot] = (f32x4){0.f, 0.f, 0.f, 0.f};

    __syncthreads();

    float S1[2], S2[2];
    #pragma unroll
    for (int pg = 0; pg < 2; ++pg) {
        S1[pg] = sAB[pg * 16 + llo];
        S2[pg] = sAB[32 + pg * 16 + llo];
    }

    #define LDT(o) (*reinterpret_cast<const uint4*>(tile + (o)))

    #pragma unroll
    for (int pg = 0; pg < 2; ++pg) {
        const int ipx = i0 + pg;
        const int jpx = j0 + llo;

        // -- geometry: L-half addresses + weights (H = +64 immediate) --
        unsigned A[4], B[2];
        float    AG[4], BG[2];
        if (w == 0) {
            geoW<-1,-1,-1, 0>(S1[pg], S2[pg], ipx, iorg, jpx, jorg, g16, A, AG, B, BG);
        } else if (w == 1) {
            geoW<-1, 1, 0,-1>(S1[pg], S2[pg], ipx, iorg, jpx, jorg, g16, A, AG, B, BG);
        } else if (w == 2) {
            geoW< 1,-1, 1, 0>(S1[pg], S2[pg], ipx, iorg, jpx, jorg, g16, A, AG, B, BG);
        } else {
            geoW< 1, 1, 0, 1>(S1[pg], S2[pg], ipx, iorg, jpx, jorg, g16, A, AG, B, BG);
        }
        unsigned cAddr = pixb(pg + 2, llo + 2, g16) + (cs ? 64u : 0u);

        // -- hoisted load burst: 13 ds_read_b128 (H-halves via offset:64) --
        uint4 La[4], Ha[4];
        #pragma unroll
        for (int p = 0; p < 4; ++p) {
            La[p] = LDT(A[p]);
            Ha[p] = LDT(A[p] + 64);
        }
        uint4 Lb[2], Hb[2];
        #pragma unroll
        for (int p = 0; p < 2; ++p) {
            Lb[p] = LDT(B[p]);
            Hb[p] = LDT(B[p] + 64);
        }
        bf16x8 bc;
        {
            union { uint4 u; bf16x8 b; } cv; cv.u = LDT(cAddr); bc = cv.b;
        }

        // -- consume (same fp element order as r5, packed 2-wide) --
        f32x2 v0[4], v1[4];
        #pragma unroll
        for (int q = 0; q < 4; ++q) { v0[q] = (f32x2){0.f,0.f}; v1[q] = (f32x2){0.f,0.f}; }
        #pragma unroll
        for (int p = 0; p < 4; ++p) fma16p(La[p], Ha[p], AG[p], v0, v1);
        bf16x8 bA0 = packv2(v0), bA1 = packv2(v1);

        f32x2 u0[4], u1[4];
        #pragma unroll
        for (int q = 0; q < 4; ++q) { u0[q] = (f32x2){0.f,0.f}; u1[q] = (f32x2){0.f,0.f}; }
        #pragma unroll
        for (int p = 0; p < 2; ++p) fma16p(Lb[p], Hb[p], BG[p], u0, u1);
        bf16x8 bB0 = packv2(u0), bB1 = packv2(u1);

        #pragma unroll
        for (int ot = 0; ot < 4; ++ot) {
            acc[pg][ot] = __builtin_amdgcn_mfma_f32_16x16x32_bf16(Ata[0][ot], bA0, acc[pg][ot], 0, 0, 0);
            acc[pg][ot] = __builtin_amdgcn_mfma_f32_16x16x32_bf16(Ata[1][ot], bA1, acc[pg][ot], 0, 0, 0);
            acc[pg][ot] = __builtin_amdgcn_mfma_f32_16x16x32_bf16(Atb[0][ot], bB0, acc[pg][ot], 0, 0, 0);
            acc[pg][ot] = __builtin_amdgcn_mfma_f32_16x16x32_bf16(Atb[1][ot], bB1, acc[pg][ot], 0, 0, 0);
        }
        if (w & 1) {
            acc[pg][2] = __builtin_amdgcn_mfma_f32_16x16x32_bf16(Ac0, bc, acc[pg][2], 0, 0, 0);
            acc[pg][3] = __builtin_amdgcn_mfma_f32_16x16x32_bf16(Ac1, bc, acc[pg][3], 0, 0, 0);
        } else {
            acc[pg][0] = __builtin_amdgcn_mfma_f32_16x16x32_bf16(Ac0, bc, acc[pg][0], 0, 0, 0);
            acc[pg][1] = __builtin_amdgcn_mfma_f32_16x16x32_bf16(Ac1, bc, acc[pg][1], 0, 0, 0);
        }
    }
    #undef LDT

    // ---- cross-wave K-reduce through LDS (validated r4/r6) ----
    __syncthreads();
    #pragma unroll
    for (int pg = 0; pg < 2; ++pg)
      #pragma unroll
      for (int ot = 0; ot < 4; ++ot)
        *reinterpret_cast<f32x4*>(smem + ((pg*256 + w*64 + lane)*80) + ot*16) = acc[pg][ot];
    __syncthreads();
    {
        const int eq = w;
        #pragma unroll
        for (int pg = 0; pg < 2; ++pg) {
            f32x4 s = (f32x4){0.f, 0.f, 0.f, 0.f};
            #pragma unroll
            for (int ww = 0; ww < 4; ++ww)
                s += *reinterpret_cast<const f32x4*>(smem + ((pg*256 + ww*64 + lane)*80) + eq*16);
            float* ob = out + (size_t)b * COUT * HW + (size_t)(i0 + pg) * Wn + j0 + llo;
            #pragma unroll
            for (int r = 0; r < 4; ++r) {
                int o = eq * 16 + g * 4 + r;
                ob[(size_t)o * HW] = s[r] + bias[o];
            }
        }
    }
}

// ====================== FALLBACK PATH (round-2, validated) ==================

__device__ __forceinline__ unsigned pk2f(float a, float b) {
    return (unsigned)f2bf(a) | ((unsigned)f2bf(b) << 16);
}

__global__ void prep_weights(const float* __restrict__ weight,
                             unsigned short* __restrict__ Wtb) {
    int e = blockIdx.x * 256 + threadIdx.x;
    if (e >= COUT * KDIM) return;
    int o = e / KDIM, k = e % KDIM;
    int n = k >> 6, c = k & 63;
    int u = n % 3, v = n / 3;
    float w0 = weight[((o * CIN + c) * 3 + 0) * 3 + v];
    float w2 = weight[((o * CIN + c) * 3 + 2) * 3 + v];
    float val = (u == 0) ? w0 : ((u == 1) ? (-w0 - w2) : w2);
    Wtb[o * KDIM + k] = f2bf(val);
}

template<int DX, int DY>
__device__ __forceinline__ void gatherG(const float* __restrict__ xb,
    float s1, float s2, int i, int jj, int klocal,
    char* myrow, unsigned swz, int c0s, int c1s)
{
    int ix0 = 0, ix1 = 0; float wx0 = 1.f, wx1 = 0.f;
    if (DX != 0) {
        float px = (float)DX * s1 + (float)(i + 1);
        float fx = floorf(px);
        float qx0 = fminf(fmaxf(fx, 0.f), 129.f);
        float qx1 = fminf(fmaxf(fx + 1.f, 0.f), 129.f);
        wx0 = 1.f + (qx0 - px); wx1 = 1.f - (qx1 - px);
        ix0 = (int)qx0; ix1 = (int)qx1;
    } else { ix0 = i + 1; }
    int iy0 = 0, iy1 = 0; float wy0 = 1.f, wy1 = 0.f;
    if (DY != 0) {
        float py = (float)DY * s2 + (float)(jj + 1);
        float fy = floorf(py);
        float qy0 = fminf(fmaxf(fy, 0.f), 129.f);
        float qy1 = fminf(fmaxf(fy + 1.f, 0.f), 129.f);
        wy0 = 1.f + (qy0 - py); wy1 = 1.f - (qy1 - py);
        iy0 = (int)qy0; iy1 = (int)qy1;
    } else { iy0 = jj + 1; }

    constexpr int NX = (DX ? 2 : 1), NY = (DY ? 2 : 1), NT = NX * NY;
    unsigned idx[NT]; float g[NT];
    const int   ixs[2] = { ix0, ix1 };  const float wxs[2] = { wx0, wx1 };
    const int   iys[2] = { iy0, iy1 };  const float wys[2] = { wy0, wy1 };
    #pragma unroll
    for (int xi = 0; xi < NX; ++xi)
      #pragma unroll
      for (int yi = 0; yi < NY; ++yi) {
        int ix = ixs[xi], iy = iys[yi];
        bool ok = (ix >= 1) && (ix <= Hn) && (iy >= 1) && (iy <= Wn);
        int cx = min(max(ix, 1), Hn) - 1;
        int cy = min(max(iy, 1), Wn) - 1;
        idx[xi * NY + yi] = (unsigned)(cx * Wn + cy);
        g[xi * NY + yi]   = ok ? wxs[xi] * wys[yi] : 0.f;
      }
    for (int c0 = c0s; c0 < c1s; c0 += 8) {
        float v[8];
        #pragma unroll
        for (int cc = 0; cc < 8; ++cc) {
            unsigned coff = (unsigned)(c0 + cc) * HW;
            float acc2 = 0.f;
            #pragma unroll
            for (int tp = 0; tp < NT; ++tp)
                acc2 = fmaf(g[tp], xb[coff + idx[tp]], acc2);
            v[cc] = acc2;
        }
        uint4 d;
        d.x = pk2f(v[0], v[1]); d.y = pk2f(v[2], v[3]);
        d.z = pk2f(v[4], v[5]); d.w = pk2f(v[6], v[7]);
        unsigned addr = (unsigned)(klocal + c0) * 2u;
        *reinterpret_cast<uint4*>(myrow + (addr ^ swz)) = d;
    }
}

template<int KS>
__device__ __forceinline__ void mfma_phase(const char* emap,
    const unsigned short* __restrict__ Wtb,
    int w, int lane, int passbyte, f32x4 acc[4])
{
    const int llo = lane & 15, lhi = lane >> 4;
    const unsigned prow = (unsigned)(w * 16 + llo);
    const unsigned psw  = (prow & 7u) << 4;
    const char* erow = emap + prow * EROW;
    const char* wtb  = (const char*)Wtb + passbyte + lhi * 16;
    #pragma unroll
    for (int s = 0; s < KS; ++s) {
        unsigned kb = (unsigned)(s * 64 + lhi * 16);
        bf16x8 bf = *reinterpret_cast<const bf16x8*>(erow + (kb ^ psw));
        #pragma unroll
        for (int ot = 0; ot < 4; ++ot) {
            const char* ap = wtb + (ot * 16 + llo) * WROW + s * 64;
            bf16x8 af = *reinterpret_cast<const bf16x8*>(ap);
            acc[ot] = __builtin_amdgcn_mfma_f32_16x16x32_bf16(af, bf, acc[ot], 0, 0, 0);
        }
    }
}

__global__ __launch_bounds__(256, 3) void ddconv_mfma(
    const float* __restrict__ x, const float* __restrict__ alpha,
    const unsigned short* __restrict__ Wtb, const float* __restrict__ bias,
    float* __restrict__ out)
{
    __shared__ __align__(16) char emap[64 * EROW];
    const int blk  = blockIdx.x;
    const int b    = blk >> 8;
    const int rem  = blk & 255;
    const int i    = rem >> 1;
    const int j0   = (rem & 1) << 6;
    const int t    = threadIdx.x;
    const int lane = t & 63;
    const int w    = t >> 6;
    const int jj   = j0 + lane;
    const float* xb = x + (size_t)b * CIN * HW;
    float a = alpha[(b * Hn + i) * Wn + jj];
    float sa, ca;
    sincosf(a, &sa, &ca);
    const float s1 = ca + sa, s2 = ca - sa;
    char* myrow = emap + lane * EROW;
    const unsigned swz = (unsigned)((lane & 7) << 4);
    f32x4 acc[4];
    #pragma unroll
    for (int ot = 0; ot < 4; ++ot) acc[ot] = (f32x4){0.f, 0.f, 0.f, 0.f};
    if (w == 0)      { gatherG<-1,-1>(xb, s1, s2, i, jj,   0, myrow, swz,  0, 48); }
    else if (w == 1) { gatherG<-1,-1>(xb, s1, s2, i, jj,   0, myrow, swz, 48, 64);
                       gatherG<-1, 0>(xb, s1, s2, i, jj,  64, myrow, swz,  0, 64); }
    else if (w == 2) { gatherG<-1, 1>(xb, s1, s2, i, jj, 128, myrow, swz,  0, 48); }
    else             { gatherG<-1, 1>(xb, s1, s2, i, jj, 128, myrow, swz, 48, 64);
                       gatherG< 0,-1>(xb, s1, s2, i, jj, 192, myrow, swz,  0, 64); }
    __syncthreads();
    mfma_phase<8>(emap, Wtb, w, lane, 0, acc);
    __syncthreads();
    if (w == 0)      { gatherG< 1,-1>(xb, s1, s2, i, jj, 128, myrow, swz,  0, 56); }
    else if (w == 1) { gatherG< 1,-1>(xb, s1, s2, i, jj, 128, myrow, swz, 56, 64);
                       gatherG< 1, 1>(xb, s1, s2, i, jj, 256, myrow, swz,  0, 48); }
    else if (w == 2) { gatherG< 1, 1>(xb, s1, s2, i, jj, 256, myrow, swz, 48, 64);
                       gatherG< 0, 1>(xb, s1, s2, i, jj,  64, myrow, swz,  0, 64); }
    else             { gatherG< 1, 0>(xb, s1, s2, i, jj, 192, myrow, swz,  0, 64);
                       gatherG< 0, 0>(xb, s1, s2, i, jj,   0, myrow, swz,  0, 64); }
    __syncthreads();
    mfma_phase<10>(emap, Wtb, w, lane, 512, acc);
    const int llo = lane & 15, lhi = lane >> 4;
    float* ob = out + (size_t)b * COUT * HW + (size_t)i * Wn + j0 + w * 16 + llo;
    #pragma unroll
    for (int ot = 0; ot < 4; ++ot)
      #pragma unroll
      for (int r = 0; r < 4; ++r) {
        int o = ot * 16 + lhi * 4 + r;
        ob[(size_t)o * HW] = acc[ot][r] + bias[o];
      }
}

// ============================================================================

extern "C" void kernel_launch(void* const* d_in, const int* in_sizes, int n_in,
                              void* d_out, int out_size, void* d_ws, size_t ws_size,
                              hipStream_t stream) {
    const float* x      = (const float*)d_in[0];
    const float* alpha  = (const float*)d_in[1];
    const float* weight = (const float*)d_in[2];
    const float* bias   = (const float*)d_in[3];
    float* out = (float*)d_out;

    const size_t WT_BYTES = (size_t)COUT * KDIM * 2;          // 73728
    const size_t XT_BYTES = (size_t)4 * HW * CIN * 2;         // 8388608

    if (ws_size >= WT_BYTES + XT_BYTES) {
        unsigned short* Wtb2 = (unsigned short*)d_ws;
        unsigned short* xt   = (unsigned short*)((char*)d_ws + WT_BYTES);
        prep_fused<<<1168, 256, 0, stream>>>(x, weight, xt, Wtb2);
        ddconv_ws3<<<4 * (Hn / 2) * (Wn / 16), 256, 0, stream>>>(xt, alpha, Wtb2, bias, out);
    } else {
        unsigned short* Wtb = (unsigned short*)d_ws;          // round-2 layout
        prep_weights<<<(COUT * KDIM + 255) / 256, 256, 0, stream>>>(weight, Wtb);
        ddconv_mfma<<<4 * Hn * (Wn / 64), 256, 0, stream>>>(x, alpha, Wtb, bias, out);
    }
}